// Round 1
// baseline (317.953 us; speedup 1.0000x reference)
//
#include <hip/hip_runtime.h>
#include <hip/hip_bf16.h>
#include <stdint.h>

#define DIM     1024
#define SEQ     2048
#define NTOK    4096
#define HEADS   8
#define DH      64
#define AINNER  512
#define FFI     4096
#define FUSED   8832
#define HCOLS   4608   // 512 attn-out cols + 4096 gated-ff cols

typedef __attribute__((ext_vector_type(8))) short short8;
typedef __attribute__((ext_vector_type(4))) short short4v;
typedef __attribute__((ext_vector_type(4))) float f32x4;

__device__ __forceinline__ short f2bf(float f) {
  union { float f; uint32_t u; } v; v.f = f;
  uint32_t r = v.u + 0x7fffu + ((v.u >> 16) & 1u);
  return (short)(r >> 16);
}
__device__ __forceinline__ float bf2f(short s) {
  union { uint32_t u; float f; } v; v.u = ((uint32_t)(uint16_t)s) << 16;
  return v.f;
}
__device__ __forceinline__ void g2l16(const void* g, void* l) {
  __builtin_amdgcn_global_load_lds((const __attribute__((address_space(1))) void*)g,
                                   (__attribute__((address_space(3))) void*)l, 16, 0, 0);
}

// ---------------- transpose + f32->bf16 convert -----------------------------
// w_fused (1024 x 8832) f32  ->  WtF (8832 x 1024) bf16
__global__ __launch_bounds__(256) void k_transpose_wf(const float* __restrict__ src,
                                                      short* __restrict__ dst) {
  __shared__ short tile[32][33];
  int c0 = blockIdx.x * 32;             // src col / dst row
  int r0 = blockIdx.y * 32;             // src row / dst col
  int tx = threadIdx.x & 31, ty = threadIdx.x >> 5;
#pragma unroll
  for (int i = 0; i < 32; i += 8)
    tile[ty + i][tx] = f2bf(src[(size_t)(r0 + ty + i) * FUSED + c0 + tx]);
  __syncthreads();
#pragma unroll
  for (int i = 0; i < 32; i += 8)
    dst[(size_t)(c0 + ty + i) * DIM + r0 + tx] = tile[tx][ty + i];
}

// stacked [w_attn_out (512x1024); w_ff_out (4096x1024)] -> Wt2 (1024 x 4608) bf16
__global__ __launch_bounds__(256) void k_transpose_w2(const float* __restrict__ wao,
                                                      const float* __restrict__ wfo,
                                                      short* __restrict__ dst) {
  __shared__ short tile[32][33];
  int c0 = blockIdx.x * 32;             // src col (0..1023) / dst row
  int r0 = blockIdx.y * 32;             // src row (0..4607) / dst col
  int tx = threadIdx.x & 31, ty = threadIdx.x >> 5;
#pragma unroll
  for (int i = 0; i < 32; i += 8) {
    int r = r0 + ty + i;
    float v = (r < AINNER) ? wao[(size_t)r * DIM + c0 + tx]
                           : wfo[(size_t)(r - AINNER) * DIM + c0 + tx];
    tile[ty + i][tx] = f2bf(v);
  }
  __syncthreads();
#pragma unroll
  for (int i = 0; i < 32; i += 8)
    dst[(size_t)(c0 + ty + i) * HCOLS + r0 + tx] = tile[tx][ty + i];
}

// ---------------- layernorm (per token row of 1024) -------------------------
__global__ __launch_bounds__(256) void k_ln(const float* __restrict__ x,
                                            const float* __restrict__ gamma,
                                            short* __restrict__ xn) {
  int row = blockIdx.x;
  int t = threadIdx.x;
  const float4* xr = (const float4*)(x + (size_t)row * DIM);
  float4 v = xr[t];
  float s = v.x + v.y + v.z + v.w;
  float s2 = v.x * v.x + v.y * v.y + v.z * v.z + v.w * v.w;
#pragma unroll
  for (int m = 1; m < 64; m <<= 1) { s += __shfl_xor(s, m); s2 += __shfl_xor(s2, m); }
  __shared__ float red[8];
  int w = t >> 6;
  if ((t & 63) == 0) { red[w] = s; red[4 + w] = s2; }
  __syncthreads();
  s = red[0] + red[1] + red[2] + red[3];
  s2 = red[4] + red[5] + red[6] + red[7];
  float mu = s * (1.f / DIM);
  float rs = rsqrtf(s2 * (1.f / DIM) - mu * mu + 1e-5f);
  const float4* g4 = (const float4*)gamma;
  float4 g = g4[t];
  short4v o;
  o.x = f2bf((v.x - mu) * rs * g.x);
  o.y = f2bf((v.y - mu) * rs * g.y);
  o.z = f2bf((v.z - mu) * rs * g.z);
  o.w = f2bf((v.w - mu) * rs * g.w);
  ((short4v*)(xn + (size_t)row * DIM))[t] = o;
}

// ---------------- B^T GEMM, 128x128 tile, BK=64, m97 structure --------------
// C(M x N) = A(M x K, row-major, stride lda) @ Bt(N x K, row-major, stride ldb)^T
// MODE 0: qkv split write; 1: silu(gate) -> H; 2: H *= ffx; 3: f32 out write
template <int MODE>
__global__ __launch_bounds__(256) void k_gemm(const short* __restrict__ A, int lda,
                                              const short* __restrict__ Bt, int ldb,
                                              int K, void* __restrict__ out0,
                                              void* __restrict__ out1,
                                              void* __restrict__ out2) {
  __shared__ __align__(16) short As[128 * 64];
  __shared__ __align__(16) short Bs[128 * 64];
  int t = threadIdx.x, l = t & 63, w = t >> 6;
  int nt = blockIdx.x, mt = blockIdx.y;
  int mBase = mt * 128, nBase = nt * 128;

  // staging: lane l of wave w fills LDS bytes w*1024 + l*16 (+i*4096);
  // source chunk XOR-swizzled so reads can de-conflict (row&7 == l>>3 here)
  int srow = w * 8 + (l >> 3);
  int schunk = (l & 7) ^ (l >> 3);
  const short* Arow0 = A + (size_t)(mBase + srow) * lda + schunk * 8;
  const short* Brow0 = Bt + (size_t)(nBase + srow) * ldb + schunk * 8;
  short* Asl = As + w * 512 + l * 8;
  short* Bsl = Bs + w * 512 + l * 8;

  f32x4 zero = {0.f, 0.f, 0.f, 0.f};
  f32x4 acc[4][4];
#pragma unroll
  for (int m = 0; m < 4; ++m)
#pragma unroll
    for (int n = 0; n < 4; ++n) acc[m][n] = zero;

  int wr = (w >> 1) * 64, wc = (w & 1) * 64;
  int c0 = l & 15, kg = l >> 4, cx = l & 7;

  for (int kt = 0; kt < K; kt += 64) {
    __syncthreads();  // previous compute done before overwrite
#pragma unroll
    for (int i = 0; i < 4; ++i) {
      g2l16(Arow0 + (size_t)(i * 32) * lda + kt, Asl + i * 2048);
      g2l16(Brow0 + (size_t)(i * 32) * ldb + kt, Bsl + i * 2048);
    }
    __syncthreads();  // vmcnt drained -> LDS tiles ready
    short8 af[4][2], bfr[4][2];
#pragma unroll
    for (int m = 0; m < 4; ++m)
#pragma unroll
      for (int kk = 0; kk < 2; ++kk) {
        int r = wr + m * 16 + c0;
        int ch = (kk * 4 + kg) ^ cx;
        af[m][kk] = *(const short8*)(As + r * 64 + ch * 8);
      }
#pragma unroll
    for (int n = 0; n < 4; ++n)
#pragma unroll
      for (int kk = 0; kk < 2; ++kk) {
        int r = wc + n * 16 + c0;
        int ch = (kk * 4 + kg) ^ cx;
        bfr[n][kk] = *(const short8*)(Bs + r * 64 + ch * 8);
      }
#pragma unroll
    for (int m = 0; m < 4; ++m)
#pragma unroll
      for (int n = 0; n < 4; ++n)
#pragma unroll
        for (int kk = 0; kk < 2; ++kk)
          acc[m][n] = __builtin_amdgcn_mfma_f32_16x16x32_bf16(af[m][kk], bfr[n][kk],
                                                              acc[m][n], 0, 0, 0);
  }

  int r0 = (l >> 4) * 4;
#pragma unroll
  for (int m = 0; m < 4; ++m)
#pragma unroll
    for (int n = 0; n < 4; ++n)
#pragma unroll
      for (int r = 0; r < 4; ++r) {
        float val = acc[m][n][r];
        int row = mBase + wr + m * 16 + r0 + r;
        int col = nBase + wc + n * 16 + c0;
        if (MODE == 0) {
          if (col < AINNER)
            ((short*)out0)[(size_t)row * AINNER + col] = f2bf(val);
          else if (col < AINNER + DH)
            ((short*)out1)[(size_t)row * DH + (col - AINNER)] = f2bf(val);
          else  // V^T: vt[(b*64 + d)*2048 + n]
            ((short*)out2)[((size_t)(row >> 11) * DH + (col - AINNER - DH)) * SEQ +
                           (row & (SEQ - 1))] = f2bf(val);
        } else if (MODE == 1) {
          float sg = val / (1.f + __expf(-val));
          ((short*)out0)[(size_t)row * HCOLS + AINNER + col] = f2bf(sg);
        } else if (MODE == 2) {
          short* Hp = (short*)out0;
          size_t idx = (size_t)row * HCOLS + AINNER + col;
          Hp[idx] = f2bf(bf2f(Hp[idx]) * val);
        } else {
          ((float*)out0)[(size_t)row * DIM + col] = val;
        }
      }
}

// ---------------- flash attention: 128-query tile per block -----------------
// grid (16 qtiles, 16 b*h); K/V shared across heads. Writes H cols 0..511.
__global__ __launch_bounds__(256) void k_attn(const short* __restrict__ qb,
                                              const short* __restrict__ kb,
                                              const short* __restrict__ vt,
                                              short* __restrict__ H) {
  __shared__ __align__(16) short Qs[128 * 64];
  __shared__ __align__(16) short KVs[128 * 64];  // K tile, then reused as V^T tile
  __shared__ __align__(16) short Ps[4][32 * 128];
  int t = threadIdx.x, l = t & 63, w = t >> 6;
  int qt = blockIdx.x, bh = blockIdx.y;
  int b = bh >> 3, h = bh & 7;
  int q0 = qt * 128;

  int srow = w * 8 + (l >> 3);
  int schunk = (l & 7) ^ (l >> 3);
  {  // stage Q once (swizzled like GEMM tiles)
    const short* Qg = qb + (size_t)(b * SEQ + q0 + srow) * AINNER + h * DH + schunk * 8;
    short* qs = Qs + w * 512 + l * 8;
#pragma unroll
    for (int i = 0; i < 4; ++i) g2l16(Qg + (size_t)(i * 32) * AINNER, qs + i * 2048);
  }
  const short* Kg = kb + (size_t)(b * SEQ + srow) * DH + schunk * 8;
  int vrow = w * 4 + (l >> 4);                  // V^T tile row (d), +i*16
  int vchunk = (l & 15) ^ (vrow & 7);
  const short* Vg = vt + (size_t)b * DH * SEQ + (size_t)vrow * SEQ + vchunk * 8;
  short* kvdst = KVs + w * 512 + l * 8;

  float m_run[2][4], l_run[2][4];
  f32x4 zero = {0.f, 0.f, 0.f, 0.f};
  f32x4 Oacc[2][4];
#pragma unroll
  for (int m = 0; m < 2; ++m) {
#pragma unroll
    for (int r = 0; r < 4; ++r) { m_run[m][r] = -1e30f; l_run[m][r] = 0.f; }
#pragma unroll
    for (int n = 0; n < 4; ++n) Oacc[m][n] = zero;
  }
  int c0 = l & 15, kg = l >> 4, cx = l & 7;
  short* pw = Ps[w];

  for (int kv0 = 0; kv0 < SEQ; kv0 += 128) {
    __syncthreads();  // prev PV reads of KVs done
#pragma unroll
    for (int i = 0; i < 4; ++i)
      g2l16(Kg + (size_t)(kv0 + i * 32) * DH, kvdst + i * 2048);
    __syncthreads();  // K tile (and Q on first iter) ready

    f32x4 sacc[2][8];
#pragma unroll
    for (int m = 0; m < 2; ++m)
#pragma unroll
      for (int n = 0; n < 8; ++n) sacc[m][n] = zero;
#pragma unroll
    for (int kk = 0; kk < 2; ++kk) {
      short8 aq[2];
#pragma unroll
      for (int m = 0; m < 2; ++m) {
        int rr = w * 32 + m * 16 + c0;
        int ch = (kk * 4 + kg) ^ cx;
        aq[m] = *(const short8*)(Qs + rr * 64 + ch * 8);
      }
#pragma unroll
      for (int n = 0; n < 8; ++n) {
        int rr = n * 16 + c0;
        int ch = (kk * 4 + kg) ^ cx;
        short8 bk = *(const short8*)(KVs + rr * 64 + ch * 8);
#pragma unroll
        for (int m = 0; m < 2; ++m)
          sacc[m][n] = __builtin_amdgcn_mfma_f32_16x16x32_bf16(aq[m], bk, sacc[m][n], 0, 0, 0);
      }
    }
    // online softmax: lane owns rows (l>>4)*4+r of each 16-row frag
#pragma unroll
    for (int m = 0; m < 2; ++m)
#pragma unroll
      for (int r = 0; r < 4; ++r) {
        float mx = -1e30f;
#pragma unroll
        for (int n = 0; n < 8; ++n) {
          sacc[m][n][r] *= 0.125f;
          mx = fmaxf(mx, sacc[m][n][r]);
        }
#pragma unroll
        for (int msk = 1; msk < 16; msk <<= 1) mx = fmaxf(mx, __shfl_xor(mx, msk));
        float nm = fmaxf(m_run[m][r], mx);
        float corr = __expf(m_run[m][r] - nm);
        m_run[m][r] = nm;
        float rs = 0.f;
#pragma unroll
        for (int n = 0; n < 8; ++n) {
          float p = __expf(sacc[m][n][r] - nm);
          sacc[m][n][r] = p;
          rs += p;
        }
#pragma unroll
        for (int msk = 1; msk < 16; msk <<= 1) rs += __shfl_xor(rs, msk);
        l_run[m][r] = l_run[m][r] * corr + rs;
#pragma unroll
        for (int n = 0; n < 4; ++n) Oacc[m][n][r] *= corr;
      }
    // P (D-layout) -> wave-local swizzled LDS [32][128]
#pragma unroll
    for (int m = 0; m < 2; ++m)
#pragma unroll
      for (int n = 0; n < 8; ++n)
#pragma unroll
        for (int r = 0; r < 4; ++r) {
          int pr = m * 16 + (l >> 4) * 4 + r;
          int pc = n * 16 + c0;
          pw[pr * 128 + ((pc >> 3) ^ (pr & 7)) * 8 + (pc & 7)] = f2bf(sacc[m][n][r]);
        }
    __syncthreads();  // all waves done reading K tile
#pragma unroll
    for (int i = 0; i < 4; ++i)
      g2l16(Vg + kv0 + (size_t)(i * 16) * SEQ, kvdst + i * 2048);
    __syncthreads();  // V^T tile ready
    // PV: O += P(32x128) @ V(128x64)
#pragma unroll
    for (int kk = 0; kk < 4; ++kk) {
      short8 ap[2];
#pragma unroll
      for (int m = 0; m < 2; ++m) {
        int pr = m * 16 + c0;
        int ch = (kk * 4 + kg) ^ (pr & 7);
        ap[m] = *(const short8*)(pw + pr * 128 + ch * 8);
      }
#pragma unroll
      for (int n = 0; n < 4; ++n) {
        int vr = n * 16 + c0;
        int ch = (kk * 4 + kg) ^ (vr & 7);
        short8 bv = *(const short8*)(KVs + vr * 128 + ch * 8);
#pragma unroll
        for (int m = 0; m < 2; ++m)
          Oacc[m][n] = __builtin_amdgcn_mfma_f32_16x16x32_bf16(ap[m], bv, Oacc[m][n], 0, 0, 0);
      }
    }
  }
#pragma unroll
  for (int m = 0; m < 2; ++m)
#pragma unroll
    for (int r = 0; r < 4; ++r) {
      float inv = 1.f / l_run[m][r];
      int row = b * SEQ + q0 + w * 32 + m * 16 + (l >> 4) * 4 + r;
#pragma unroll
      for (int n = 0; n < 4; ++n) {
        int col = h * DH + n * 16 + c0;
        H[(size_t)row * HCOLS + col] = f2bf(Oacc[m][n][r] * inv);
      }
    }
}

// ----------------------------------------------------------------------------
extern "C" void kernel_launch(void* const* d_in, const int* in_sizes, int n_in,
                              void* d_out, int out_size, void* d_ws, size_t ws_size,
                              hipStream_t stream) {
  const float* x     = (const float*)d_in[0];
  const float* gamma = (const float*)d_in[1];
  const float* w_f   = (const float*)d_in[2];
  const float* w_ao  = (const float*)d_in[3];
  const float* w_fo  = (const float*)d_in[4];
  float* out = (float*)d_out;

  char* ws = (char*)d_ws;
  size_t o = 0;
  short* WtF = (short*)(ws + o); o += (size_t)FUSED * DIM * 2;   // 18.1 MB
  short* Wt2 = (short*)(ws + o); o += (size_t)DIM * HCOLS * 2;   //  9.4 MB
  short* xn  = (short*)(ws + o); o += (size_t)NTOK * DIM * 2;    //  8.4 MB
  short* qb  = (short*)(ws + o); o += (size_t)NTOK * AINNER * 2; //  4.2 MB
  short* kbf = (short*)(ws + o); o += (size_t)NTOK * DH * 2;     //  0.5 MB
  short* vtb = (short*)(ws + o); o += (size_t)NTOK * DH * 2;     //  0.5 MB
  short* H   = (short*)(ws + o); o += (size_t)NTOK * HCOLS * 2;  // 37.7 MB  (~79 MB total)

  k_transpose_wf<<<dim3(FUSED / 32, DIM / 32), 256, 0, stream>>>(w_f, WtF);
  k_transpose_w2<<<dim3(DIM / 32, HCOLS / 32), 256, 0, stream>>>(w_ao, w_fo, Wt2);
  k_ln<<<NTOK, 256, 0, stream>>>(x, gamma, xn);
  // qkv: cols 0..639 of fused proj
  k_gemm<0><<<dim3(5, 32), 256, 0, stream>>>(xn, DIM, WtF, DIM, DIM, qb, kbf, vtb);
  k_attn<<<dim3(16, 16), 256, 0, stream>>>(qb, kbf, vtb, H);
  // gate: fused cols 4736..8831 -> silu -> H cols 512..4607
  k_gemm<1><<<dim3(32, 32), 256, 0, stream>>>(xn, DIM, WtF + (size_t)(640 + FFI) * DIM, DIM,
                                              DIM, H, nullptr, nullptr);
  // ffx: fused cols 640..4735 -> H *= ffx
  k_gemm<2><<<dim3(32, 32), 256, 0, stream>>>(xn, DIM, WtF + (size_t)640 * DIM, DIM,
                                              DIM, H, nullptr, nullptr);
  // out = H (4096x4608) @ [w_attn_out; w_ff_out]
  k_gemm<3><<<dim3(8, 32), 256, 0, stream>>>(H, HCOLS, Wt2, HCOLS, HCOLS, out,
                                             nullptr, nullptr);
}

// Round 2
// 285.260 us; speedup vs baseline: 1.1146x; 1.1146x over previous
//
#include <hip/hip_runtime.h>
#include <hip/hip_bf16.h>
#include <stdint.h>

#define DIM     1024
#define SEQ     2048
#define NTOK    4096
#define HEADS   8
#define DH      64
#define AINNER  512
#define FFI     4096
#define FUSED   8832
#define HCOLS   4608   // 512 attn-out cols + 4096 gated-ff cols

typedef __attribute__((ext_vector_type(8))) short short8;
typedef __attribute__((ext_vector_type(4))) short short4v;
typedef __attribute__((ext_vector_type(4))) float f32x4;

__device__ __forceinline__ short f2bf(float f) {
  union { float f; uint32_t u; } v; v.f = f;
  uint32_t r = v.u + 0x7fffu + ((v.u >> 16) & 1u);
  return (short)(r >> 16);
}
__device__ __forceinline__ float bf2f(short s) {
  union { uint32_t u; float f; } v; v.u = ((uint32_t)(uint16_t)s) << 16;
  return v.f;
}
__device__ __forceinline__ void g2l16(const void* g, void* l) {
  __builtin_amdgcn_global_load_lds((const __attribute__((address_space(1))) void*)g,
                                   (__attribute__((address_space(3))) void*)l, 16, 0, 0);
}

// ---------------- transpose + f32->bf16 convert -----------------------------
__global__ __launch_bounds__(256) void k_transpose_wf(const float* __restrict__ src,
                                                      short* __restrict__ dst) {
  __shared__ short tile[32][33];
  int c0 = blockIdx.x * 32;
  int r0 = blockIdx.y * 32;
  int tx = threadIdx.x & 31, ty = threadIdx.x >> 5;
#pragma unroll
  for (int i = 0; i < 32; i += 8)
    tile[ty + i][tx] = f2bf(src[(size_t)(r0 + ty + i) * FUSED + c0 + tx]);
  __syncthreads();
#pragma unroll
  for (int i = 0; i < 32; i += 8)
    dst[(size_t)(c0 + ty + i) * DIM + r0 + tx] = tile[tx][ty + i];
}

__global__ __launch_bounds__(256) void k_transpose_w2(const float* __restrict__ wao,
                                                      const float* __restrict__ wfo,
                                                      short* __restrict__ dst) {
  __shared__ short tile[32][33];
  int c0 = blockIdx.x * 32;
  int r0 = blockIdx.y * 32;
  int tx = threadIdx.x & 31, ty = threadIdx.x >> 5;
#pragma unroll
  for (int i = 0; i < 32; i += 8) {
    int r = r0 + ty + i;
    float v = (r < AINNER) ? wao[(size_t)r * DIM + c0 + tx]
                           : wfo[(size_t)(r - AINNER) * DIM + c0 + tx];
    tile[ty + i][tx] = f2bf(v);
  }
  __syncthreads();
#pragma unroll
  for (int i = 0; i < 32; i += 8)
    dst[(size_t)(c0 + ty + i) * HCOLS + r0 + tx] = tile[tx][ty + i];
}

// ---------------- layernorm -------------------------------------------------
__global__ __launch_bounds__(256) void k_ln(const float* __restrict__ x,
                                            const float* __restrict__ gamma,
                                            short* __restrict__ xn) {
  int row = blockIdx.x;
  int t = threadIdx.x;
  const float4* xr = (const float4*)(x + (size_t)row * DIM);
  float4 v = xr[t];
  float s = v.x + v.y + v.z + v.w;
  float s2 = v.x * v.x + v.y * v.y + v.z * v.z + v.w * v.w;
#pragma unroll
  for (int m = 1; m < 64; m <<= 1) { s += __shfl_xor(s, m); s2 += __shfl_xor(s2, m); }
  __shared__ float red[8];
  int w = t >> 6;
  if ((t & 63) == 0) { red[w] = s; red[4 + w] = s2; }
  __syncthreads();
  s = red[0] + red[1] + red[2] + red[3];
  s2 = red[4] + red[5] + red[6] + red[7];
  float mu = s * (1.f / DIM);
  float rs = rsqrtf(s2 * (1.f / DIM) - mu * mu + 1e-5f);
  const float4* g4 = (const float4*)gamma;
  float4 g = g4[t];
  short4v o;
  o.x = f2bf((v.x - mu) * rs * g.x);
  o.y = f2bf((v.y - mu) * rs * g.y);
  o.z = f2bf((v.z - mu) * rs * g.z);
  o.w = f2bf((v.w - mu) * rs * g.w);
  ((short4v*)(xn + (size_t)row * DIM))[t] = o;
}

// ---------------- pipelined B^T GEMM ----------------------------------------
// 128x128 tile, BK=64, 512 threads (8 waves 2x4, 64x32 slab each).
// 4-deep LDS ring (128 KB dynamic), counted vmcnt(8), 1 barrier/K-step.
// MODE 0: qkv+ffx split write; 1: H = silu(gate)*H (RMW); 2: f32 out
template <int MODE>
__global__ __launch_bounds__(512, 2) void gemm_p(const short* __restrict__ A, int lda,
                                                 const short* __restrict__ Bt, int ldb,
                                                 int K, void* __restrict__ out0,
                                                 void* __restrict__ out1,
                                                 void* __restrict__ out2,
                                                 void* __restrict__ out3) {
  extern __shared__ __align__(16) short SA[];  // slot*16384: A 8192 shorts, B 8192
  int tid = threadIdx.x, l = tid & 63, w = tid >> 6;
  int gx = gridDim.x;
  int nwg = gx * gridDim.y;
  int hw = blockIdx.y * gx + blockIdx.x;
  int qq = nwg >> 3;                       // all grids divisible by 8
  int tile = (hw & 7) * qq + (hw >> 3);    // XCD-contiguous remap (m157/m204)
  int bx = tile % gx, by = tile / gx;
  int mBase = by * 128, nBase = bx * 128;

  // staging addresses: instr i covers rows i*64 + w*8 + (l>>3), chunk (l&7)^(l>>3)
  int srow = w * 8 + (l >> 3);
  int cs = (l & 7) ^ (l >> 3);
  const short* Ag = A + (size_t)(mBase + srow) * lda + cs * 8;
  const short* Bg = Bt + (size_t)(nBase + srow) * ldb + cs * 8;
  short* ldsA = SA + w * 512 + l * 8;      // + slot*16384 + i*4096
  short* ldsB = ldsA + 8192;

  int NT = K >> 6;
  for (int tt = 0; tt < 3; ++tt) {         // prologue: stage tiles 0,1,2
    int slot = tt & 3;
#pragma unroll
    for (int i = 0; i < 2; ++i) {
      g2l16(Ag + (size_t)(i * 64) * lda + tt * 64, ldsA + slot * 16384 + i * 4096);
      g2l16(Bg + (size_t)(i * 64) * ldb + tt * 64, ldsB + slot * 16384 + i * 4096);
    }
  }

  int wr = w >> 2, wc = w & 3;
  int c0 = l & 15, kg = l >> 4, cx = l & 7;
  f32x4 zero = {0.f, 0.f, 0.f, 0.f};
  f32x4 acc[4][2];
#pragma unroll
  for (int m = 0; m < 4; ++m)
#pragma unroll
    for (int n = 0; n < 2; ++n) acc[m][n] = zero;

  for (int kt = 0; kt < NT; ++kt) {
    // counted wait: tiles kt+1, kt+2 (8 loads) may stay in flight
    if (kt + 2 < NT)      asm volatile("s_waitcnt vmcnt(8)\ns_barrier" ::: "memory");
    else if (kt + 1 < NT) asm volatile("s_waitcnt vmcnt(4)\ns_barrier" ::: "memory");
    else                  asm volatile("s_waitcnt vmcnt(0)\ns_barrier" ::: "memory");
    int slot = kt & 3;
    const short* Ab = SA + slot * 16384;
    const short* Bb = Ab + 8192;
    short8 af[4][2], bfr[2][2];
#pragma unroll
    for (int m = 0; m < 4; ++m)
#pragma unroll
      for (int kk = 0; kk < 2; ++kk)
        af[m][kk] = *(const short8*)(Ab + (wr * 64 + m * 16 + c0) * 64 + ((kk * 4 + kg) ^ cx) * 8);
#pragma unroll
    for (int n = 0; n < 2; ++n)
#pragma unroll
      for (int kk = 0; kk < 2; ++kk)
        bfr[n][kk] = *(const short8*)(Bb + (wc * 32 + n * 16 + c0) * 64 + ((kk * 4 + kg) ^ cx) * 8);
    int ts = kt + 3;                       // stage tile kt+3 into freed slot
    if (ts < NT) {
      int s2 = ts & 3;
#pragma unroll
      for (int i = 0; i < 2; ++i) {
        g2l16(Ag + (size_t)(i * 64) * lda + ts * 64, ldsA + s2 * 16384 + i * 4096);
        g2l16(Bg + (size_t)(i * 64) * ldb + ts * 64, ldsB + s2 * 16384 + i * 4096);
      }
    }
    __builtin_amdgcn_s_setprio(1);
#pragma unroll
    for (int m = 0; m < 4; ++m)
#pragma unroll
      for (int n = 0; n < 2; ++n)
#pragma unroll
        for (int kk = 0; kk < 2; ++kk)
          acc[m][n] = __builtin_amdgcn_mfma_f32_16x16x32_bf16(af[m][kk], bfr[n][kk],
                                                              acc[m][n], 0, 0, 0);
    __builtin_amdgcn_s_setprio(0);
  }

  int r0 = (l >> 4) * 4;
#pragma unroll
  for (int m = 0; m < 4; ++m)
#pragma unroll
    for (int n = 0; n < 2; ++n)
#pragma unroll
      for (int r = 0; r < 4; ++r) {
        float val = acc[m][n][r];
        int row = mBase + wr * 64 + m * 16 + r0 + r;
        int col = nBase + wc * 32 + n * 16 + c0;
        if (MODE == 0) {
          if (col < AINNER)
            ((short*)out0)[(size_t)row * AINNER + col] = f2bf(val);
          else if (col < AINNER + DH)
            ((short*)out1)[(size_t)row * DH + (col - AINNER)] = f2bf(val);
          else if (col < AINNER + 2 * DH)
            ((short*)out2)[((size_t)(row >> 11) * DH + (col - AINNER - DH)) * SEQ +
                           (row & (SEQ - 1))] = f2bf(val);
          else  // ffx -> H cols 512..4607
            ((short*)out3)[(size_t)row * HCOLS + AINNER + (col - 640)] = f2bf(val);
        } else if (MODE == 1) {
          short* Hp = (short*)out0;
          size_t idx = (size_t)row * HCOLS + AINNER + col;
          float sg = val / (1.f + __expf(-val));
          Hp[idx] = f2bf(sg * bf2f(Hp[idx]));
        } else {
          ((float*)out0)[(size_t)row * DIM + col] = val;
        }
      }
}

// ---------------- flash attention (unchanged) -------------------------------
__global__ __launch_bounds__(256) void k_attn(const short* __restrict__ qb,
                                              const short* __restrict__ kb,
                                              const short* __restrict__ vt,
                                              short* __restrict__ H) {
  __shared__ __align__(16) short Qs[128 * 64];
  __shared__ __align__(16) short KVs[128 * 64];
  __shared__ __align__(16) short Ps[4][32 * 128];
  int t = threadIdx.x, l = t & 63, w = t >> 6;
  int qt = blockIdx.x, bh = blockIdx.y;
  int b = bh >> 3, h = bh & 7;
  int q0 = qt * 128;

  int srow = w * 8 + (l >> 3);
  int schunk = (l & 7) ^ (l >> 3);
  {
    const short* Qg = qb + (size_t)(b * SEQ + q0 + srow) * AINNER + h * DH + schunk * 8;
    short* qs = Qs + w * 512 + l * 8;
#pragma unroll
    for (int i = 0; i < 4; ++i) g2l16(Qg + (size_t)(i * 32) * AINNER, qs + i * 2048);
  }
  const short* Kg = kb + (size_t)(b * SEQ + srow) * DH + schunk * 8;
  int vrow = w * 4 + (l >> 4);
  int vchunk = (l & 15) ^ (vrow & 7);
  const short* Vg = vt + (size_t)b * DH * SEQ + (size_t)vrow * SEQ + vchunk * 8;
  short* kvdst = KVs + w * 512 + l * 8;

  float m_run[2][4], l_run[2][4];
  f32x4 zero = {0.f, 0.f, 0.f, 0.f};
  f32x4 Oacc[2][4];
#pragma unroll
  for (int m = 0; m < 2; ++m) {
#pragma unroll
    for (int r = 0; r < 4; ++r) { m_run[m][r] = -1e30f; l_run[m][r] = 0.f; }
#pragma unroll
    for (int n = 0; n < 4; ++n) Oacc[m][n] = zero;
  }
  int c0 = l & 15, kg = l >> 4, cx = l & 7;
  short* pw = Ps[w];

  for (int kv0 = 0; kv0 < SEQ; kv0 += 128) {
    __syncthreads();
#pragma unroll
    for (int i = 0; i < 4; ++i)
      g2l16(Kg + (size_t)(kv0 + i * 32) * DH, kvdst + i * 2048);
    __syncthreads();

    f32x4 sacc[2][8];
#pragma unroll
    for (int m = 0; m < 2; ++m)
#pragma unroll
      for (int n = 0; n < 8; ++n) sacc[m][n] = zero;
#pragma unroll
    for (int kk = 0; kk < 2; ++kk) {
      short8 aq[2];
#pragma unroll
      for (int m = 0; m < 2; ++m) {
        int rr = w * 32 + m * 16 + c0;
        int ch = (kk * 4 + kg) ^ cx;
        aq[m] = *(const short8*)(Qs + rr * 64 + ch * 8);
      }
#pragma unroll
      for (int n = 0; n < 8; ++n) {
        int rr = n * 16 + c0;
        int ch = (kk * 4 + kg) ^ cx;
        short8 bk = *(const short8*)(KVs + rr * 64 + ch * 8);
#pragma unroll
        for (int m = 0; m < 2; ++m)
          sacc[m][n] = __builtin_amdgcn_mfma_f32_16x16x32_bf16(aq[m], bk, sacc[m][n], 0, 0, 0);
      }
    }
#pragma unroll
    for (int m = 0; m < 2; ++m)
#pragma unroll
      for (int r = 0; r < 4; ++r) {
        float mx = -1e30f;
#pragma unroll
        for (int n = 0; n < 8; ++n) {
          sacc[m][n][r] *= 0.125f;
          mx = fmaxf(mx, sacc[m][n][r]);
        }
#pragma unroll
        for (int msk = 1; msk < 16; msk <<= 1) mx = fmaxf(mx, __shfl_xor(mx, msk));
        float nm = fmaxf(m_run[m][r], mx);
        float corr = __expf(m_run[m][r] - nm);
        m_run[m][r] = nm;
        float rs = 0.f;
#pragma unroll
        for (int n = 0; n < 8; ++n) {
          float p = __expf(sacc[m][n][r] - nm);
          sacc[m][n][r] = p;
          rs += p;
        }
#pragma unroll
        for (int msk = 1; msk < 16; msk <<= 1) rs += __shfl_xor(rs, msk);
        l_run[m][r] = l_run[m][r] * corr + rs;
#pragma unroll
        for (int n = 0; n < 4; ++n) Oacc[m][n][r] *= corr;
      }
#pragma unroll
    for (int m = 0; m < 2; ++m)
#pragma unroll
      for (int n = 0; n < 8; ++n)
#pragma unroll
        for (int r = 0; r < 4; ++r) {
          int pr = m * 16 + (l >> 4) * 4 + r;
          int pc = n * 16 + c0;
          pw[pr * 128 + ((pc >> 3) ^ (pr & 7)) * 8 + (pc & 7)] = f2bf(sacc[m][n][r]);
        }
    __syncthreads();
#pragma unroll
    for (int i = 0; i < 4; ++i)
      g2l16(Vg + kv0 + (size_t)(i * 16) * SEQ, kvdst + i * 2048);
    __syncthreads();
#pragma unroll
    for (int kk = 0; kk < 4; ++kk) {
      short8 ap[2];
#pragma unroll
      for (int m = 0; m < 2; ++m) {
        int pr = m * 16 + c0;
        int ch = (kk * 4 + kg) ^ (pr & 7);
        ap[m] = *(const short8*)(pw + pr * 128 + ch * 8);
      }
#pragma unroll
      for (int n = 0; n < 4; ++n) {
        int vr = n * 16 + c0;
        int ch = (kk * 4 + kg) ^ (vr & 7);
        short8 bv = *(const short8*)(KVs + vr * 128 + ch * 8);
#pragma unroll
        for (int m = 0; m < 2; ++m)
          Oacc[m][n] = __builtin_amdgcn_mfma_f32_16x16x32_bf16(ap[m], bv, Oacc[m][n], 0, 0, 0);
      }
    }
  }
#pragma unroll
  for (int m = 0; m < 2; ++m)
#pragma unroll
    for (int r = 0; r < 4; ++r) {
      float inv = 1.f / l_run[m][r];
      int row = b * SEQ + q0 + w * 32 + m * 16 + (l >> 4) * 4 + r;
#pragma unroll
      for (int n = 0; n < 4; ++n) {
        int col = h * DH + n * 16 + c0;
        H[(size_t)row * HCOLS + col] = f2bf(Oacc[m][n][r] * inv);
      }
    }
}

// ----------------------------------------------------------------------------
extern "C" void kernel_launch(void* const* d_in, const int* in_sizes, int n_in,
                              void* d_out, int out_size, void* d_ws, size_t ws_size,
                              hipStream_t stream) {
  const float* x     = (const float*)d_in[0];
  const float* gamma = (const float*)d_in[1];
  const float* w_f   = (const float*)d_in[2];
  const float* w_ao  = (const float*)d_in[3];
  const float* w_fo  = (const float*)d_in[4];
  float* out = (float*)d_out;

  char* ws = (char*)d_ws;
  size_t o = 0;
  short* WtF = (short*)(ws + o); o += (size_t)FUSED * DIM * 2;
  short* Wt2 = (short*)(ws + o); o += (size_t)DIM * HCOLS * 2;
  short* xn  = (short*)(ws + o); o += (size_t)NTOK * DIM * 2;
  short* qb  = (short*)(ws + o); o += (size_t)NTOK * AINNER * 2;
  short* kbf = (short*)(ws + o); o += (size_t)NTOK * DH * 2;
  short* vtb = (short*)(ws + o); o += (size_t)NTOK * DH * 2;
  short* H   = (short*)(ws + o); o += (size_t)NTOK * HCOLS * 2;

  k_transpose_wf<<<dim3(FUSED / 32, DIM / 32), 256, 0, stream>>>(w_f, WtF);
  k_transpose_w2<<<dim3(DIM / 32, HCOLS / 32), 256, 0, stream>>>(w_ao, w_fo, Wt2);
  k_ln<<<NTOK, 256, 0, stream>>>(x, gamma, xn);
  // q,k,v,ffx: fused cols 0..4735 (contiguous) in one GEMM
  gemm_p<0><<<dim3(37, 32), 512, 131072, stream>>>(xn, DIM, WtF, DIM, DIM,
                                                   qb, kbf, vtb, H);
  k_attn<<<dim3(16, 16), 256, 0, stream>>>(qb, kbf, vtb, H);
  // gate: fused cols 4736..8831 -> H = silu(gate) * H
  gemm_p<1><<<dim3(32, 32), 512, 131072, stream>>>(xn, DIM, WtF + (size_t)4736 * DIM, DIM,
                                                   DIM, H, nullptr, nullptr, nullptr);
  // out = H (4096x4608) @ [w_attn_out; w_ff_out]
  gemm_p<2><<<dim3(8, 32), 512, 131072, stream>>>(H, HCOLS, Wt2, HCOLS, HCOLS, out,
                                                  nullptr, nullptr, nullptr);
}

// Round 4
// 254.935 us; speedup vs baseline: 1.2472x; 1.1190x over previous
//
#include <hip/hip_runtime.h>
#include <hip/hip_bf16.h>
#include <stdint.h>

#define DIM     1024
#define SEQ     2048
#define NTOK    4096
#define HEADS   8
#define DH      64
#define AINNER  512
#define FFI     4096
#define FUSED   8832
#define HCOLS   4608   // 512 attn-out cols + 4096 gated-ff cols

typedef __attribute__((ext_vector_type(8))) short short8;
typedef __attribute__((ext_vector_type(4))) short short4v;
typedef __attribute__((ext_vector_type(4))) float f32x4;

__device__ __forceinline__ short f2bf(float f) {
  union { float f; uint32_t u; } v; v.f = f;
  uint32_t r = v.u + 0x7fffu + ((v.u >> 16) & 1u);
  return (short)(r >> 16);
}
__device__ __forceinline__ float bf2f(short s) {
  union { uint32_t u; float f; } v; v.u = ((uint32_t)(uint16_t)s) << 16;
  return v.f;
}
__device__ __forceinline__ void g2l16(const void* g, void* l) {
  __builtin_amdgcn_global_load_lds((const __attribute__((address_space(1))) void*)g,
                                   (__attribute__((address_space(3))) void*)l, 16, 0, 0);
}

// ---------------- transpose + f32->bf16 convert -----------------------------
__global__ __launch_bounds__(256) void k_transpose_wf(const float* __restrict__ src,
                                                      short* __restrict__ dst) {
  __shared__ short tile[32][33];
  int c0 = blockIdx.x * 32;
  int r0 = blockIdx.y * 32;
  int tx = threadIdx.x & 31, ty = threadIdx.x >> 5;
#pragma unroll
  for (int i = 0; i < 32; i += 8)
    tile[ty + i][tx] = f2bf(src[(size_t)(r0 + ty + i) * FUSED + c0 + tx]);
  __syncthreads();
#pragma unroll
  for (int i = 0; i < 32; i += 8)
    dst[(size_t)(c0 + ty + i) * DIM + r0 + tx] = tile[tx][ty + i];
}

__global__ __launch_bounds__(256) void k_transpose_w2(const float* __restrict__ wao,
                                                      const float* __restrict__ wfo,
                                                      short* __restrict__ dst) {
  __shared__ short tile[32][33];
  int c0 = blockIdx.x * 32;
  int r0 = blockIdx.y * 32;
  int tx = threadIdx.x & 31, ty = threadIdx.x >> 5;
#pragma unroll
  for (int i = 0; i < 32; i += 8) {
    int r = r0 + ty + i;
    float v = (r < AINNER) ? wao[(size_t)r * DIM + c0 + tx]
                           : wfo[(size_t)(r - AINNER) * DIM + c0 + tx];
    tile[ty + i][tx] = f2bf(v);
  }
  __syncthreads();
#pragma unroll
  for (int i = 0; i < 32; i += 8)
    dst[(size_t)(c0 + ty + i) * HCOLS + r0 + tx] = tile[tx][ty + i];
}

// ---------------- layernorm -------------------------------------------------
__global__ __launch_bounds__(256) void k_ln(const float* __restrict__ x,
                                            const float* __restrict__ gamma,
                                            short* __restrict__ xn) {
  int row = blockIdx.x;
  int t = threadIdx.x;
  const float4* xr = (const float4*)(x + (size_t)row * DIM);
  float4 v = xr[t];
  float s = v.x + v.y + v.z + v.w;
  float s2 = v.x * v.x + v.y * v.y + v.z * v.z + v.w * v.w;
#pragma unroll
  for (int m = 1; m < 64; m <<= 1) { s += __shfl_xor(s, m); s2 += __shfl_xor(s2, m); }
  __shared__ float red[8];
  int w = t >> 6;
  if ((t & 63) == 0) { red[w] = s; red[4 + w] = s2; }
  __syncthreads();
  s = red[0] + red[1] + red[2] + red[3];
  s2 = red[4] + red[5] + red[6] + red[7];
  float mu = s * (1.f / DIM);
  float rs = rsqrtf(s2 * (1.f / DIM) - mu * mu + 1e-5f);
  const float4* g4 = (const float4*)gamma;
  float4 g = g4[t];
  short4v o;
  o.x = f2bf((v.x - mu) * rs * g.x);
  o.y = f2bf((v.y - mu) * rs * g.y);
  o.z = f2bf((v.z - mu) * rs * g.z);
  o.w = f2bf((v.w - mu) * rs * g.w);
  ((short4v*)(xn + (size_t)row * DIM))[t] = o;
}

// ---------------- pipelined B^T GEMM (unchanged) ----------------------------
template <int MODE>
__global__ __launch_bounds__(512, 2) void gemm_p(const short* __restrict__ A, int lda,
                                                 const short* __restrict__ Bt, int ldb,
                                                 int K, void* __restrict__ out0,
                                                 void* __restrict__ out1,
                                                 void* __restrict__ out2,
                                                 void* __restrict__ out3) {
  extern __shared__ __align__(16) short SA[];
  int tid = threadIdx.x, l = tid & 63, w = tid >> 6;
  int gx = gridDim.x;
  int nwg = gx * gridDim.y;
  int hw = blockIdx.y * gx + blockIdx.x;
  int qq = nwg >> 3;
  int tile = (hw & 7) * qq + (hw >> 3);
  int bx = tile % gx, by = tile / gx;
  int mBase = by * 128, nBase = bx * 128;

  int srow = w * 8 + (l >> 3);
  int cs = (l & 7) ^ (l >> 3);
  const short* Ag = A + (size_t)(mBase + srow) * lda + cs * 8;
  const short* Bg = Bt + (size_t)(nBase + srow) * ldb + cs * 8;
  short* ldsA = SA + w * 512 + l * 8;
  short* ldsB = ldsA + 8192;

  int NT = K >> 6;
  for (int tt = 0; tt < 3; ++tt) {
    int slot = tt & 3;
#pragma unroll
    for (int i = 0; i < 2; ++i) {
      g2l16(Ag + (size_t)(i * 64) * lda + tt * 64, ldsA + slot * 16384 + i * 4096);
      g2l16(Bg + (size_t)(i * 64) * ldb + tt * 64, ldsB + slot * 16384 + i * 4096);
    }
  }

  int wr = w >> 2, wc = w & 3;
  int c0 = l & 15, kg = l >> 4, cx = l & 7;
  f32x4 zero = {0.f, 0.f, 0.f, 0.f};
  f32x4 acc[4][2];
#pragma unroll
  for (int m = 0; m < 4; ++m)
#pragma unroll
    for (int n = 0; n < 2; ++n) acc[m][n] = zero;

  for (int kt = 0; kt < NT; ++kt) {
    if (kt + 2 < NT)      asm volatile("s_waitcnt vmcnt(8)\ns_barrier" ::: "memory");
    else if (kt + 1 < NT) asm volatile("s_waitcnt vmcnt(4)\ns_barrier" ::: "memory");
    else                  asm volatile("s_waitcnt vmcnt(0)\ns_barrier" ::: "memory");
    int slot = kt & 3;
    const short* Ab = SA + slot * 16384;
    const short* Bb = Ab + 8192;
    short8 af[4][2], bfr[2][2];
#pragma unroll
    for (int m = 0; m < 4; ++m)
#pragma unroll
      for (int kk = 0; kk < 2; ++kk)
        af[m][kk] = *(const short8*)(Ab + (wr * 64 + m * 16 + c0) * 64 + ((kk * 4 + kg) ^ cx) * 8);
#pragma unroll
    for (int n = 0; n < 2; ++n)
#pragma unroll
      for (int kk = 0; kk < 2; ++kk)
        bfr[n][kk] = *(const short8*)(Bb + (wc * 32 + n * 16 + c0) * 64 + ((kk * 4 + kg) ^ cx) * 8);
    int ts = kt + 3;
    if (ts < NT) {
      int s2 = ts & 3;
#pragma unroll
      for (int i = 0; i < 2; ++i) {
        g2l16(Ag + (size_t)(i * 64) * lda + ts * 64, ldsA + s2 * 16384 + i * 4096);
        g2l16(Bg + (size_t)(i * 64) * ldb + ts * 64, ldsB + s2 * 16384 + i * 4096);
      }
    }
    __builtin_amdgcn_s_setprio(1);
#pragma unroll
    for (int m = 0; m < 4; ++m)
#pragma unroll
      for (int n = 0; n < 2; ++n)
#pragma unroll
        for (int kk = 0; kk < 2; ++kk)
          acc[m][n] = __builtin_amdgcn_mfma_f32_16x16x32_bf16(af[m][kk], bfr[n][kk],
                                                              acc[m][n], 0, 0, 0);
    __builtin_amdgcn_s_setprio(0);
  }

  int r0 = (l >> 4) * 4;
#pragma unroll
  for (int m = 0; m < 4; ++m)
#pragma unroll
    for (int n = 0; n < 2; ++n)
#pragma unroll
      for (int r = 0; r < 4; ++r) {
        float val = acc[m][n][r];
        int row = mBase + wr * 64 + m * 16 + r0 + r;
        int col = nBase + wc * 32 + n * 16 + c0;
        if (MODE == 0) {
          if (col < AINNER)
            ((short*)out0)[(size_t)row * AINNER + col] = f2bf(val);
          else if (col < AINNER + DH)
            ((short*)out1)[(size_t)row * DH + (col - AINNER)] = f2bf(val);
          else if (col < AINNER + 2 * DH)
            ((short*)out2)[((size_t)(row >> 11) * DH + (col - AINNER - DH)) * SEQ +
                           (row & (SEQ - 1))] = f2bf(val);
          else
            ((short*)out3)[(size_t)row * HCOLS + AINNER + (col - 640)] = f2bf(val);
        } else if (MODE == 1) {
          short* Hp = (short*)out0;
          size_t idx = (size_t)row * HCOLS + AINNER + col;
          float sg = val / (1.f + __expf(-val));
          Hp[idx] = f2bf(sg * bf2f(Hp[idx]));
        } else {
          ((float*)out0)[(size_t)row * DIM + col] = val;
        }
      }
}

// ---------------- flash attention: 64-query tile, 2 blocks/CU ---------------
// grid (32 qtiles, 16 b*h). LDS: Q 8K + K 16K + V 16K + P 16K = 56KB.
__global__ __launch_bounds__(256) void k_attn(const short* __restrict__ qb,
                                              const short* __restrict__ kb,
                                              const short* __restrict__ vt,
                                              short* __restrict__ H) {
  __shared__ __align__(16) short Qs[64 * 64];
  __shared__ __align__(16) short Ks[128 * 64];
  __shared__ __align__(16) short Vs[64 * 128];
  __shared__ __align__(16) short Ps[4][16 * 128];
  int t = threadIdx.x, l = t & 63, w = t >> 6;
  int qt = blockIdx.x, bh = blockIdx.y;
  int b = bh >> 3, h = bh & 7;
  int q0 = qt * 64;

  int srow = w * 8 + (l >> 3);
  int schunk = (l & 7) ^ (l >> 3);
  {  // stage Q (2 instrs: rows 0..63)
    const short* Qg = qb + (size_t)(b * SEQ + q0 + srow) * AINNER + h * DH + schunk * 8;
    short* qs = Qs + w * 512 + l * 8;
#pragma unroll
    for (int i = 0; i < 2; ++i) g2l16(Qg + (size_t)(i * 32) * AINNER, qs + i * 2048);
  }
  const short* Kg = kb + (size_t)(b * SEQ + srow) * DH + schunk * 8;
  short* ksl = Ks + w * 512 + l * 8;
  int vrow = w * 4 + (l >> 4);
  int vchunk = (l & 15) ^ (vrow & 7);
  const short* Vg = vt + (size_t)b * DH * SEQ + (size_t)vrow * SEQ + vchunk * 8;
  short* vsl = Vs + w * 512 + l * 8;

  // prologue: stage K(0), V(0)
#pragma unroll
  for (int i = 0; i < 4; ++i) {
    g2l16(Kg + (size_t)(i * 32) * DH, ksl + i * 2048);
    g2l16(Vg + (size_t)(i * 16) * SEQ, vsl + i * 2048);
  }

  float m_run[4], l_run[4];
  f32x4 zero = {0.f, 0.f, 0.f, 0.f};
  f32x4 Oacc[4];
#pragma unroll
  for (int r = 0; r < 4; ++r) { m_run[r] = -1e30f; l_run[r] = 0.f; }
#pragma unroll
  for (int n = 0; n < 4; ++n) Oacc[n] = zero;

  int c0 = l & 15, kg = l >> 4, cx = l & 7;
  short* pw = Ps[w];

  for (int kv0 = 0; kv0 < SEQ; kv0 += 128) {
    asm volatile("s_waitcnt vmcnt(0)\ns_barrier" ::: "memory");  // K,V (and Q) ready

    // QK^T: S(16x128) per wave; lane holds k-col c0, q-rows (l>>4)*4+r
    f32x4 sacc[8];
#pragma unroll
    for (int n = 0; n < 8; ++n) sacc[n] = zero;
#pragma unroll
    for (int kk = 0; kk < 2; ++kk) {
      int rr = w * 16 + c0;
      short8 aq = *(const short8*)(Qs + rr * 64 + ((kk * 4 + kg) ^ cx) * 8);
#pragma unroll
      for (int n = 0; n < 8; ++n) {
        int kr = n * 16 + c0;
        short8 bk = *(const short8*)(Ks + kr * 64 + ((kk * 4 + kg) ^ cx) * 8);
        sacc[n] = __builtin_amdgcn_mfma_f32_16x16x32_bf16(aq, bk, sacc[n], 0, 0, 0);
      }
    }
    // online softmax: reduce across the 16 lanes sharing l>>4 (masks 1,2,4,8)
#pragma unroll
    for (int r = 0; r < 4; ++r) {
      float mx = -1e30f;
#pragma unroll
      for (int n = 0; n < 8; ++n) {
        sacc[n][r] *= 0.125f;
        mx = fmaxf(mx, sacc[n][r]);
      }
#pragma unroll
      for (int msk = 1; msk < 16; msk <<= 1) mx = fmaxf(mx, __shfl_xor(mx, msk));
      float nm = fmaxf(m_run[r], mx);
      float corr = __expf(m_run[r] - nm);
      m_run[r] = nm;
      float rs = 0.f;
#pragma unroll
      for (int n = 0; n < 8; ++n) {
        float p = __expf(sacc[n][r] - nm);
        sacc[n][r] = p;
        rs += p;
      }
#pragma unroll
      for (int msk = 1; msk < 16; msk <<= 1) rs += __shfl_xor(rs, msk);
      l_run[r] = l_run[r] * corr + rs;
      Oacc[0][r] *= corr; Oacc[1][r] *= corr; Oacc[2][r] *= corr; Oacc[3][r] *= corr;
    }
    // P -> wave-local swizzled LDS [16][128]
#pragma unroll
    for (int n = 0; n < 8; ++n)
#pragma unroll
      for (int r = 0; r < 4; ++r) {
        int pr = (l >> 4) * 4 + r;
        int pc = n * 16 + c0;
        pw[pr * 128 + ((pc >> 3) ^ (pr & 7)) * 8 + (pc & 7)] = f2bf(sacc[n][r]);
      }
    asm volatile("s_waitcnt lgkmcnt(0)" ::: "memory");  // own P writes landed
    // PV: O(16x64) += P(16x128) @ V(128x64)
#pragma unroll
    for (int kk = 0; kk < 4; ++kk) {
      int pr = c0;
      short8 ap = *(const short8*)(pw + pr * 128 + ((kk * 4 + kg) ^ cx) * 8);
#pragma unroll
      for (int n = 0; n < 4; ++n) {
        int vr = n * 16 + c0;
        short8 bv = *(const short8*)(Vs + vr * 128 + ((kk * 4 + kg) ^ (vr & 7)) * 8);
        Oacc[n] = __builtin_amdgcn_mfma_f32_16x16x32_bf16(ap, bv, Oacc[n], 0, 0, 0);
      }
    }
    __syncthreads();  // all waves done reading Ks, Vs
    int nx = kv0 + 128;
    if (nx < SEQ) {
#pragma unroll
      for (int i = 0; i < 4; ++i) {
        g2l16(Kg + (size_t)(nx + i * 32) * DH, ksl + i * 2048);
        g2l16(Vg + nx + (size_t)(i * 16) * SEQ, vsl + i * 2048);
      }
    }
  }
#pragma unroll
  for (int r = 0; r < 4; ++r) {
    float inv = 1.f / l_run[r];
    int row = b * SEQ + q0 + w * 16 + (l >> 4) * 4 + r;
#pragma unroll
    for (int n = 0; n < 4; ++n) {
      int col = h * DH + n * 16 + c0;
      H[(size_t)row * HCOLS + col] = f2bf(Oacc[n][r] * inv);
    }
  }
}

// ----------------------------------------------------------------------------
extern "C" void kernel_launch(void* const* d_in, const int* in_sizes, int n_in,
                              void* d_out, int out_size, void* d_ws, size_t ws_size,
                              hipStream_t stream) {
  const float* x     = (const float*)d_in[0];
  const float* gamma = (const float*)d_in[1];
  const float* w_f   = (const float*)d_in[2];
  const float* w_ao  = (const float*)d_in[3];
  const float* w_fo  = (const float*)d_in[4];
  float* out = (float*)d_out;

  char* ws = (char*)d_ws;
  size_t o = 0;
  short* WtF = (short*)(ws + o); o += (size_t)FUSED * DIM * 2;
  short* Wt2 = (short*)(ws + o); o += (size_t)DIM * HCOLS * 2;
  short* xn  = (short*)(ws + o); o += (size_t)NTOK * DIM * 2;
  short* qb  = (short*)(ws + o); o += (size_t)NTOK * AINNER * 2;
  short* kbf = (short*)(ws + o); o += (size_t)NTOK * DH * 2;
  short* vtb = (short*)(ws + o); o += (size_t)NTOK * DH * 2;
  short* H   = (short*)(ws + o); o += (size_t)NTOK * HCOLS * 2;

  k_transpose_wf<<<dim3(FUSED / 32, DIM / 32), 256, 0, stream>>>(w_f, WtF);
  k_transpose_w2<<<dim3(DIM / 32, HCOLS / 32), 256, 0, stream>>>(w_ao, w_fo, Wt2);
  k_ln<<<NTOK, 256, 0, stream>>>(x, gamma, xn);
  gemm_p<0><<<dim3(37, 32), 512, 131072, stream>>>(xn, DIM, WtF, DIM, DIM,
                                                   qb, kbf, vtb, H);
  k_attn<<<dim3(32, 16), 256, 0, stream>>>(qb, kbf, vtb, H);
  gemm_p<1><<<dim3(32, 32), 512, 131072, stream>>>(xn, DIM, WtF + (size_t)4736 * DIM, DIM,
                                                   DIM, H, nullptr, nullptr, nullptr);
  gemm_p<2><<<dim3(8, 32), 512, 131072, stream>>>(H, HCOLS, Wt2, HCOLS, HCOLS, out,
                                                  nullptr, nullptr, nullptr);
}